// Round 6
// baseline (342.476 us; speedup 1.0000x reference)
//
#include <hip/hip_runtime.h>
#include <math.h>

#define VOCAB 100000
#define DIM 128
#define BATCH 16384
#define CTX 10
#define NEG 10
#define NSCORE (NEG + 1)
#define EPB 8                    // batch elements per 256-thread block
#define NBLK (BATCH / EPB)       // 2048 blocks

// Fast log_sigmoid(x) = min(x,0) - log(1 + exp(-|x|)) using HW v_exp/v_log.
__device__ __forceinline__ float log_sigmoid_f(float x) {
    const float e = __expf(-fabsf(x));
    return fminf(x, 0.0f) - __logf(1.0f + e);
}

// One wave = two batch elements (lanes 0-31 / 32-63), one float4 per lane.
// Indices staged in LDS (off the VMEM pipe). VGPR capped to 64 via
// __launch_bounds__(256,8) -> 8 waves/SIMD -> ~32 waves/CU of latency hiding.
// Final reduction fused via last-block-done pattern (deterministic order).
__global__ __launch_bounds__(256, 8) void cbow_fused(
    const float* __restrict__ W_embed, const float* __restrict__ W_out,
    const int* __restrict__ ctx_ids, const int* __restrict__ tgt_ids,
    const int* __restrict__ neg_ids, float* __restrict__ partial,
    unsigned* __restrict__ counter, float* __restrict__ out)
{
    __shared__ int sCtx[EPB][CTX];
    __shared__ int sOut[EPB][NSCORE];

    const int tid = threadIdx.x;
    const int b0  = blockIdx.x * EPB;

    // --- cooperative index staging: 168 ints, one coalesced pass ---
    if (tid < EPB * CTX) {
        sCtx[tid / CTX][tid % CTX] = ctx_ids[b0 * CTX + tid];
    } else if (tid < EPB * CTX + EPB) {
        const int e = tid - EPB * CTX;
        sOut[e][0] = tgt_ids[b0 + e];
    } else if (tid < EPB * CTX + EPB + EPB * NEG) {
        const int t = tid - (EPB * CTX + EPB);
        sOut[t / NEG][1 + t % NEG] = neg_ids[b0 * NEG + t];
    }
    __syncthreads();

    const int lane = tid & 63;
    const int half = lane >> 5;
    const int l32  = lane & 31;
    const int e    = (tid >> 6) * 2 + half;   // element slot in this block

    const float4* __restrict__ We = (const float4*)W_embed;
    const float4* __restrict__ Wo = (const float4*)W_out;

    // --- context mean (incremental accumulate; reg-cap keeps ~6 in flight) ---
    float mx = 0.f, my = 0.f, mz = 0.f, mw = 0.f;
    #pragma unroll
    for (int j = 0; j < CTX; ++j) {
        const float4 v = We[(unsigned)(sCtx[e][j] * 32 + l32)];
        mx += v.x; my += v.y; mz += v.z; mw += v.w;
    }
    mx *= 0.1f; my *= 0.1f; mz *= 0.1f; mw *= 0.1f;

    // --- 11 per-lane partial dots ---
    float p[NSCORE];
    #pragma unroll
    for (int n = 0; n < NSCORE; ++n) {
        const float4 v = Wo[(unsigned)(sOut[e][n] * 32 + l32)];
        p[n] = mx * v.x + my * v.y + mz * v.z + mw * v.w;
    }

    // --- 11 interleaved 5-level butterflies within each 32-lane half ---
    #pragma unroll
    for (int off = 16; off >= 1; off >>= 1) {
        #pragma unroll
        for (int n = 0; n < NSCORE; ++n)
            p[n] += __shfl_xor(p[n], off, 64);
    }

    float loss = log_sigmoid_f(p[0]);
    #pragma unroll
    for (int n = 1; n < NSCORE; ++n)
        loss += log_sigmoid_f(-p[n]);

    if (l32 == 0) partial[b0 + e] = loss;

    // --- fused deterministic finish: last block reduces all 16384 partials ---
    __threadfence();                       // release our partial stores
    __syncthreads();
    __shared__ bool isLast;
    if (tid == 0) {
        const unsigned done =
            __hip_atomic_fetch_add(counter, 1u, __ATOMIC_ACQ_REL,
                                   __HIP_MEMORY_SCOPE_AGENT);
        isLast = (done == NBLK - 1);
    }
    __syncthreads();
    if (isLast) {
        __threadfence();                   // acquire all blocks' stores
        float v = 0.f;
        #pragma unroll
        for (int k = 0; k < BATCH / 256; ++k)
            v += partial[tid + 256 * k];
        __shared__ float s[256];
        s[tid] = v;
        __syncthreads();
        for (int stride = 128; stride > 0; stride >>= 1) {
            if (tid < stride) s[tid] += s[tid + stride];
            __syncthreads();
        }
        if (tid == 0) out[0] = -s[0] / (float)BATCH;
    }
}

extern "C" void kernel_launch(void* const* d_in, const int* in_sizes, int n_in,
                              void* d_out, int out_size, void* d_ws, size_t ws_size,
                              hipStream_t stream) {
    const float* W_embed = (const float*)d_in[0];
    const float* W_out   = (const float*)d_in[1];
    const int* ctx_ids   = (const int*)d_in[2];
    const int* tgt_ids   = (const int*)d_in[3];
    const int* neg_ids   = (const int*)d_in[4];
    float* out = (float*)d_out;

    float* partial    = (float*)d_ws;                    // 16384 floats
    unsigned* counter = (unsigned*)((char*)d_ws + BATCH * sizeof(float));

    hipMemsetAsync(counter, 0, sizeof(unsigned), stream);  // deterministic reset
    cbow_fused<<<NBLK, 256, 0, stream>>>(W_embed, W_out, ctx_ids, tgt_ids,
                                         neg_ids, partial, counter, out);
}

// Round 8
// 48.062 us; speedup vs baseline: 7.1257x; 7.1257x over previous
//
#include <hip/hip_runtime.h>
#include <math.h>

#define VOCAB 100000
#define DIM 128
#define BATCH 16384
#define CTX 10
#define NEG 10
#define NSCORE (NEG + 1)
#define NROWS (CTX + NSCORE)
#define EPB 8                    // batch elements per 256-thread block
#define NBLK (BATCH / EPB)       // 2048 blocks

// Fast log_sigmoid(x) = min(x,0) - log(1 + exp(-|x|)) using HW v_exp/v_log.
__device__ __forceinline__ float log_sigmoid_f(float x) {
    const float e = __expf(-fabsf(x));
    return fminf(x, 0.0f) - __logf(1.0f + e);
}

// One wave = two batch elements (lanes 0-31 / 32-63), one float4 per lane.
// Indices staged in LDS. Fused deterministic finish WITHOUT fences:
// relaxed agent-scope atomic stores (sc-flagged, no L2 writeback) +
// s_waitcnt vmcnt(0) + relaxed agent-scope counter RMW; last block
// re-reads partials with relaxed agent-scope atomic loads.
__global__ __launch_bounds__(256) void cbow_fused(
    const float* __restrict__ W_embed, const float* __restrict__ W_out,
    const int* __restrict__ ctx_ids, const int* __restrict__ tgt_ids,
    const int* __restrict__ neg_ids, float* __restrict__ partial,
    unsigned* __restrict__ counter, float* __restrict__ out)
{
    __shared__ int sIdx[EPB][NROWS];     // 8 x 21 indices for this block

    const int tid = threadIdx.x;
    const int b0  = blockIdx.x * EPB;

    // --- cooperative index staging: 168 ints, one coalesced pass ---
    if (tid < EPB * CTX) {
        sIdx[tid / CTX][tid % CTX] = ctx_ids[b0 * CTX + tid];
    } else if (tid < EPB * CTX + EPB) {
        const int e = tid - EPB * CTX;
        sIdx[e][CTX] = tgt_ids[b0 + e];
    } else if (tid < EPB * CTX + EPB + EPB * NEG) {
        const int t = tid - (EPB * CTX + EPB);
        sIdx[t / NEG][CTX + 1 + t % NEG] = neg_ids[b0 * NEG + t];
    }
    __syncthreads();

    const int lane = tid & 63;
    const int half = lane >> 5;
    const int l32  = lane & 31;
    const int e    = (tid >> 6) * 2 + half;   // element slot in this block

    const float4* __restrict__ We = (const float4*)W_embed;
    const float4* __restrict__ Wo = (const float4*)W_out;

    // --- context mean: 10 gathered rows, one float4 per lane ---
    float mx = 0.f, my = 0.f, mz = 0.f, mw = 0.f;
    #pragma unroll
    for (int j = 0; j < CTX; ++j) {
        const float4 v = We[(unsigned)(sIdx[e][j] * 32 + l32)];
        mx += v.x; my += v.y; mz += v.z; mw += v.w;
    }
    mx *= 0.1f; my *= 0.1f; mz *= 0.1f; mw *= 0.1f;

    // --- 11 per-lane partial dots ---
    float p[NSCORE];
    #pragma unroll
    for (int n = 0; n < NSCORE; ++n) {
        const float4 v = Wo[(unsigned)(sIdx[e][CTX + n] * 32 + l32)];
        p[n] = mx * v.x + my * v.y + mz * v.z + mw * v.w;
    }

    // --- 11 interleaved 5-level butterflies within each 32-lane half ---
    #pragma unroll
    for (int off = 16; off >= 1; off >>= 1) {
        #pragma unroll
        for (int n = 0; n < NSCORE; ++n)
            p[n] += __shfl_xor(p[n], off, 64);
    }

    float loss = log_sigmoid_f(p[0]);
    #pragma unroll
    for (int n = 1; n < NSCORE; ++n)
        loss += log_sigmoid_f(-p[n]);

    // --- per-element partial: relaxed agent-scope store (no fence) ---
    if (l32 == 0)
        __hip_atomic_store(&partial[b0 + e], loss, __ATOMIC_RELAXED,
                           __HIP_MEMORY_SCOPE_AGENT);

    // ensure this wave's store reached the coherence point, then block-sync
    asm volatile("s_waitcnt vmcnt(0)" ::: "memory");
    __syncthreads();

    __shared__ bool isLast;
    if (tid == 0) {
        const unsigned done =
            __hip_atomic_fetch_add(counter, 1u, __ATOMIC_RELAXED,
                                   __HIP_MEMORY_SCOPE_AGENT);
        isLast = (done == NBLK - 1);
    }
    __syncthreads();

    if (isLast) {
        // all 2048 blocks' partials are at the coherence point; read with
        // agent-scope relaxed atomic loads (bypass potentially-stale L2)
        float v = 0.f;
        #pragma unroll
        for (int k = 0; k < BATCH / 256; ++k)
            v += __hip_atomic_load(&partial[tid + 256 * k], __ATOMIC_RELAXED,
                                   __HIP_MEMORY_SCOPE_AGENT);
        __shared__ float s[256];
        s[tid] = v;
        __syncthreads();
        for (int stride = 128; stride > 0; stride >>= 1) {
            if (tid < stride) s[tid] += s[tid + stride];
            __syncthreads();
        }
        if (tid == 0) out[0] = -s[0] / (float)BATCH;
    }
}

extern "C" void kernel_launch(void* const* d_in, const int* in_sizes, int n_in,
                              void* d_out, int out_size, void* d_ws, size_t ws_size,
                              hipStream_t stream) {
    const float* W_embed = (const float*)d_in[0];
    const float* W_out   = (const float*)d_in[1];
    const int* ctx_ids   = (const int*)d_in[2];
    const int* tgt_ids   = (const int*)d_in[3];
    const int* neg_ids   = (const int*)d_in[4];
    float* out = (float*)d_out;

    float* partial    = (float*)d_ws;                    // 16384 floats
    unsigned* counter = (unsigned*)((char*)d_ws + BATCH * sizeof(float));

    hipMemsetAsync(counter, 0, sizeof(unsigned), stream);  // deterministic reset
    cbow_fused<<<NBLK, 256, 0, stream>>>(W_embed, W_out, ctx_ids, tgt_ids,
                                         neg_ids, partial, counter, out);
}

// Round 9
// 33.319 us; speedup vs baseline: 10.2789x; 1.4425x over previous
//
#include <hip/hip_runtime.h>
#include <math.h>

#define VOCAB 100000
#define DIM 128
#define BATCH 16384
#define CTX 10
#define NEG 10
#define NSCORE (NEG + 1)

// Fast, accurate-enough log_sigmoid(x) = min(x,0) - log(1 + exp(-|x|)).
// __expf/__logf -> v_exp_f32/v_log_f32 (~1 ulp); error averages out over
// the 180k-term mean.
__device__ __forceinline__ float log_sigmoid_f(float x) {
    const float e = __expf(-fabsf(x));
    return fminf(x, 0.0f) - __logf(1.0f + e);
}

// One wave handles TWO batch elements: lanes 0-31 -> b0, lanes 32-63 -> b1.
// Each 32-lane half owns a full D=128 row as float4 per lane.
// 4 waves/block (256 threads) -> 8 batch elements per block -> 2048 blocks.
// (Measured-best structure: R2 = 33.2 us. Fused finishes and LDS index
// staging both measured slower — see R6/R8 post-mortems.)
__global__ __launch_bounds__(256) void cbow_main(
    const float* __restrict__ W_embed, const float* __restrict__ W_out,
    const int* __restrict__ ctx_ids, const int* __restrict__ tgt_ids,
    const int* __restrict__ neg_ids, float* __restrict__ partial)
{
    const int wave = threadIdx.x >> 6;
    const int lane = threadIdx.x & 63;
    const int half = lane >> 5;          // which batch element in this wave
    const int l32  = lane & 31;          // lane within the 32-lane row
    const int b = blockIdx.x * 8 + wave * 2 + half;

    const float4* __restrict__ We = (const float4*)W_embed;
    const float4* __restrict__ Wo = (const float4*)W_out;

    // --- context mean: 10 gathered rows, each row = 32 float4 ---
    float mx = 0.f, my = 0.f, mz = 0.f, mw = 0.f;
    #pragma unroll
    for (int j = 0; j < CTX; ++j) {
        const int row = ctx_ids[b * CTX + j];   // uniform per half-wave
        const float4 v = We[(size_t)row * 32 + l32];
        mx += v.x; my += v.y; mz += v.z; mw += v.w;
    }
    mx *= 0.1f; my *= 0.1f; mz *= 0.1f; mw *= 0.1f;

    // --- 11 per-lane partial dots (target + 10 negatives) ---
    float p[NSCORE];
    #pragma unroll
    for (int n = 0; n < NSCORE; ++n) {
        const int row = (n == 0) ? tgt_ids[b] : neg_ids[b * NEG + (n - 1)];
        const float4 v = Wo[(size_t)row * 32 + l32];
        p[n] = mx * v.x + my * v.y + mz * v.z + mw * v.w;
    }

    // --- 11 independent 5-level butterflies (within each 32-lane half),
    //     interleaved level-by-level for ILP ---
    #pragma unroll
    for (int off = 16; off >= 1; off >>= 1) {
        #pragma unroll
        for (int n = 0; n < NSCORE; ++n)
            p[n] += __shfl_xor(p[n], off, 64);
    }

    // every lane of a half now holds its element's full scores
    float loss = log_sigmoid_f(p[0]);
    #pragma unroll
    for (int n = 1; n < NSCORE; ++n)
        loss += log_sigmoid_f(-p[n]);

    __shared__ float lsum[8];
    if (l32 == 0) lsum[wave * 2 + half] = loss;
    __syncthreads();
    if (threadIdx.x == 0) {
        float s = 0.f;
        #pragma unroll
        for (int i = 0; i < 8; ++i) s += lsum[i];
        partial[blockIdx.x] = s;
    }
}

// Deterministic fixed-order reduction of the 2048 block partials.
__global__ __launch_bounds__(256) void cbow_reduce(
    const float* __restrict__ partial, float* __restrict__ out)
{
    __shared__ float s[256];
    float v = 0.0f;
    #pragma unroll
    for (int k = 0; k < 8; ++k)
        v += partial[threadIdx.x + 256 * k];
    s[threadIdx.x] = v;
    __syncthreads();
    for (int stride = 128; stride > 0; stride >>= 1) {
        if (threadIdx.x < stride) s[threadIdx.x] += s[threadIdx.x + stride];
        __syncthreads();
    }
    if (threadIdx.x == 0) out[0] = -s[0] / (float)BATCH;
}

extern "C" void kernel_launch(void* const* d_in, const int* in_sizes, int n_in,
                              void* d_out, int out_size, void* d_ws, size_t ws_size,
                              hipStream_t stream) {
    const float* W_embed = (const float*)d_in[0];
    const float* W_out   = (const float*)d_in[1];
    const int* ctx_ids   = (const int*)d_in[2];
    const int* tgt_ids   = (const int*)d_in[3];
    const int* neg_ids   = (const int*)d_in[4];
    float* out = (float*)d_out;
    float* partial = (float*)d_ws;   // 2048 floats, fully rewritten each call

    cbow_main<<<BATCH / 8, 256, 0, stream>>>(W_embed, W_out, ctx_ids, tgt_ids,
                                             neg_ids, partial);
    cbow_reduce<<<1, 256, 0, stream>>>(partial, out);
}